// Round 2
// baseline (93.733 us; speedup 1.0000x reference)
//
#include <hip/hip_runtime.h>

#define HH 2048
#define WW 2048
#define KK 7
#define PADK 3
#define TILE 32
#define PADT (TILE + 6)      // 38
#define IN_STRIDE (PADT + 2) // 40, breaks pow2 bank alias
#define HS_STRIDE (TILE + 1) // 33

__global__ __launch_bounds__(256)
void UnfoldPlainFit_42477226558039_kernel(const float* __restrict__ x,
                                          float* __restrict__ out) {
    __shared__ float sIn[PADT][IN_STRIDE];   // 38 x 40 input tile (clamped)
    __shared__ float sHs[PADT][HS_STRIDE];   // horizontal plain sums
    __shared__ float sHx[PADT][HS_STRIDE];   // horizontal x-weighted sums

    const int tileR = blockIdx.y * TILE;
    const int tileC = blockIdx.x * TILE;
    const int tid = threadIdx.x;  // 0..255

    // ---- Stage 1: load 38x38 clamped input tile into LDS ----
    for (int idx = tid; idx < PADT * PADT; idx += 256) {
        int lr = idx / PADT;
        int lc = idx - lr * PADT;
        int gr = tileR - PADK + lr;
        int gc = tileC - PADK + lc;
        gr = max(0, min(HH - 1, gr));   // replication (edge) padding
        gc = max(0, min(WW - 1, gc));
        sIn[lr][lc] = x[(size_t)gr * WW + gc];
    }
    __syncthreads();

    // ---- Stage 2: horizontal sums per padded row ----
    // lanes 0..31 hit consecutive columns; 2-way row aliasing is free.
    for (int idx = tid; idx < PADT * TILE; idx += 256) {
        int lr = idx >> 5;
        int oc = idx & 31;
        float s = 0.f, wx = 0.f;
#pragma unroll
        for (int j = 0; j < KK; ++j) {
            float v = sIn[lr][oc + j];
            s += v;
            wx += (float)(j - PADK) * v;
        }
        sHs[lr][oc] = s;
        sHx[lr][oc] = wx;
    }
    __syncthreads();

    // ---- Stage 3: vertical combine; each thread owns a 1x4 pixel strip ----
    // -> 48 contiguous bytes per lane -> 3x global_store_dwordx4, fully
    //    coalesced (lane strips are consecutive in memory).
    const int row = tid >> 3;         // 0..31
    const int cg  = (tid & 7) * 4;    // 0,4,...,28

    float c0[4] = {0.f, 0.f, 0.f, 0.f};
    float c1[4] = {0.f, 0.f, 0.f, 0.f};
    float c2[4] = {0.f, 0.f, 0.f, 0.f};
#pragma unroll
    for (int i = 0; i < KK; ++i) {
        float wy = (float)(i - PADK);
#pragma unroll
        for (int u = 0; u < 4; ++u) {
            float hs = sHs[row + i][cg + u];
            float hx = sHx[row + i][cg + u];
            c2[u] += hs;
            c1[u] += wy * hs;
            c0[u] += hx;
        }
    }
    const float W196 = 1.0f / 196.0f;  // sum(x^2) over 7x7 grid = 196
    const float W49  = 1.0f / 49.0f;

    int r = tileR + row;
    int c = tileC + cg;
    float* o = out + ((size_t)r * WW + c) * 3;  // 16B-aligned: 12*(2048r+4k)
    float4 v0 = {c0[0] * W196, c1[0] * W196, c2[0] * W49,  c0[1] * W196};
    float4 v1 = {c1[1] * W196, c2[1] * W49,  c0[2] * W196, c1[2] * W196};
    float4 v2 = {c2[2] * W49,  c0[3] * W196, c1[3] * W196, c2[3] * W49};
    float4* o4 = reinterpret_cast<float4*>(o);
    o4[0] = v0;
    o4[1] = v1;
    o4[2] = v2;
}

extern "C" void kernel_launch(void* const* d_in, const int* in_sizes, int n_in,
                              void* d_out, int out_size, void* d_ws, size_t ws_size,
                              hipStream_t stream) {
    const float* x = (const float*)d_in[0];
    float* out = (float*)d_out;
    dim3 grid(WW / TILE, HH / TILE);  // 64 x 64 = 4096 blocks
    dim3 block(256);
    UnfoldPlainFit_42477226558039_kernel<<<grid, block, 0, stream>>>(x, out);
}